// Round 16
// baseline (1760.672 us; speedup 1.0000x reference)
//
#include <hip/hip_runtime.h>
#include <cfloat>
#include <cmath>
#include <cstdint>

#define DD 768
#define MM 256
#define NKB 200000
#define SLEN 512
#define KK 200      // 2*top_k
#define TOPK 100
#define SURV_CAP 1024
#define RESC 232
#define THRC 2.70f
#define MAXMARK 32768
#define DELTA 4e-5
#define NET 12      // e-tiles of 64

typedef __attribute__((ext_vector_type(8))) short bf16x8;
typedef __attribute__((ext_vector_type(4))) float f32x4;

__device__ __forceinline__ unsigned short f2bf_rne(float x) {
  unsigned u = __float_as_uint(x);
  unsigned r = (u + 0x7FFFu + ((u >> 16) & 1u)) >> 16;
  return (unsigned short)r;
}
__device__ __forceinline__ float bf2f(unsigned short us) {
  return __uint_as_float(((unsigned)us) << 16);
}
__device__ __forceinline__ void splitbf(float x, unsigned short& hi, unsigned short& lo) {
  hi = f2bf_rne(x);
  lo = f2bf_rne(x - bf2f(hi));
}

// ---------------- Kernel PT: WretT[d][e] = Wret[e][d] (LDS-tiled, coalesced both sides) ----------------
__global__ __launch_bounds__(256) void k_prepT(
    const float* __restrict__ Wret, float* __restrict__ WretT) {
  __shared__ float tile[64][65];
  int e0 = blockIdx.x * 64, d0 = blockIdx.y * 64;
  int tid = threadIdx.x;
  int r = tid >> 6, cc = tid & 63;
  for (int i = 0; i < 64; i += 4)
    tile[r + i][cc] = Wret[(size_t)(e0 + r + i) * DD + d0 + cc];
  __syncthreads();
  for (int i = 0; i < 64; i += 4)
    WretT[(size_t)(d0 + r + i) * DD + e0 + cc] = tile[cc][r + i];
}

// ------- Kernel FRONT: fused mention-mean + query (via WretT, coalesced) + m_part -------
__global__ __launch_bounds__(256) void k_front(
    const float* __restrict__ text, const int* __restrict__ msent,
    const int* __restrict__ mstart, const int* __restrict__ mlen,
    const float* __restrict__ WretT, const float* __restrict__ bret,
    const float* __restrict__ Ws1,
    double* __restrict__ q64, unsigned short* __restrict__ qb16,
    float* __restrict__ tthr, double* __restrict__ mp64,
    float* __restrict__ mp32) {
  int m = blockIdx.x;
  __shared__ double sme[DD];
  __shared__ float snorm[256];
  int tid = threadIdx.x;
  {
    int sent = msent[m], st = mstart[m], ln = mlen[m];
    const float* base = text + (size_t)sent * SLEN * DD;
    for (int d = tid; d < DD; d += 256) {
      double acc = 0.0;
      for (int s = st; s <= st + ln; ++s) acc += (double)base[(size_t)s * DD + d];
      sme[d] = acc / (double)(ln + 1);
    }
  }
  __syncthreads();
  float nloc = 0.f;
  for (int e = tid; e < DD; e += 256) {
    double aq = (double)bret[e];
    double amp = 0.0;
    for (int d = 0; d < DD; ++d) {
      double md = sme[d];
      aq  += md * (double)WretT[(size_t)d * DD + e];
      amp += md * (double)Ws1[(size_t)d * DD + e];
    }
    q64[(size_t)m * DD + e] = aq;
    qb16[(size_t)m * DD + e] = f2bf_rne((float)aq);
    mp64[(size_t)m * DD + e] = amp;
    mp32[(size_t)m * DD + e] = (float)amp;
    nloc += (float)(aq * aq);
  }
  snorm[tid] = nloc; __syncthreads();
  for (int s = 128; s > 0; s >>= 1) {
    if (tid < s) snorm[tid] += snorm[tid + s];
    __syncthreads();
  }
  if (tid == 0) tthr[m] = THRC * sqrtf(snorm[0]);
}

// ---------------- Kernel P: split+transpose Ws1[D:] -> Bt_hi/Bt_lo [e][k] bf16 ----------------
__global__ __launch_bounds__(256) void k_prep(
    const float* __restrict__ Ws1, unsigned short* __restrict__ Bth,
    unsigned short* __restrict__ Btl) {
  int e = blockIdx.x;
  for (int k = threadIdx.x; k < DD; k += 256) {
    float x = Ws1[(size_t)(DD + k) * DD + e];
    unsigned short hi, lo;
    splitbf(x, hi, lo);
    Bth[(size_t)e * DD + k] = hi;
    Btl[(size_t)e * DD + k] = lo;
  }
}

// ------- Kernel C v4: sims = q @ kb^T via bf16 MFMA; double-buffered B LDS,
// ONE barrier per 32-k step, 3-deep B prefetch, 1-deep A prefetch. Same MFMA order.
__global__ __launch_bounds__(512) void k_sims_mfma(
    const unsigned short* __restrict__ qb, const float* __restrict__ kb,
    const float* __restrict__ tthr, int* __restrict__ gcnt,
    uint2* __restrict__ gcand) {
  __shared__ unsigned short Bs[2][64 * 32];   // 8 KB, swizzled, double-buffered
  __shared__ float sthr[256];
  int n0 = blockIdx.x * 64;
  int tid = threadIdx.x;
  int lane = tid & 63, w = tid >> 6;       // 8 waves
  int h = lane >> 4, c = lane & 15;
  if (tid < 256) sthr[tid] = tthr[tid];
  f32x4 acc[2][4] = {};
  const int brow = n0 + (tid >> 3);        // stage row (64 rows x 8 thr/row)
  const int bk4  = (tid & 7) * 4;          // 4 f32 per thread
  const int bwoff = ((tid >> 3) * 64 + (tid & 7) * 8) ^ (((tid >> 3) & 7) << 4);
  auto ldB = [&](int k0) -> float4 {
    return *(const float4*)(kb + (size_t)brow * DD + k0 + bk4);
  };
  auto stB = [&](int buf, const float4 &v) {
    uint2 p;
    p.x = (unsigned)f2bf_rne(v.x) | ((unsigned)f2bf_rne(v.y) << 16);
    p.y = (unsigned)f2bf_rne(v.z) | ((unsigned)f2bf_rne(v.w) << 16);
    *(uint2*)((char*)Bs + buf * 4096 + bwoff) = p;
  };
  const unsigned short* qa0 = qb + (size_t)(w * 32 + c) * DD;
  const unsigned short* qa1 = qb + (size_t)(w * 32 + 16 + c) * DD;
  // prologue: buf0 = step0; pend1 = step1 data, pend2 = step2 data
  stB(0, ldB(0));
  float4 pend1 = ldB(32);
  float4 pend2 = ldB(64);
  bf16x8 a0 = *(const bf16x8*)(qa0 + h * 8);
  bf16x8 a1 = *(const bf16x8*)(qa1 + h * 8);
  __syncthreads();
#pragma unroll
  for (int s = 0; s < 24; ++s) {
    int cur = s & 1;
    if (s + 1 < 24) stB(cur ^ 1, pend1);     // write next buffer (prev consumers done at last barrier)
    pend1 = pend2;
    if (s + 3 < 24) pend2 = ldB((s + 3) * 32);
    int kn = (s + 1 < 24) ? (s + 1) * 32 : s * 32;
    bf16x8 a0n = *(const bf16x8*)(qa0 + kn + h * 8);   // prefetch next A (L2-hot)
    bf16x8 a1n = *(const bf16x8*)(qa1 + kn + h * 8);
#pragma unroll
    for (int nf = 0; nf < 4; ++nf) {
      int n = nf * 16 + c;
      int off = (n * 64 + h * 16) ^ ((n & 7) << 4);
      bf16x8 b = *(bf16x8*)((char*)Bs + cur * 4096 + off);
      acc[0][nf] = __builtin_amdgcn_mfma_f32_16x16x32_bf16(a0, b, acc[0][nf], 0, 0, 0);
      acc[1][nf] = __builtin_amdgcn_mfma_f32_16x16x32_bf16(a1, b, acc[1][nf], 0, 0, 0);
    }
    a0 = a0n; a1 = a1n;
    __syncthreads();   // next buffer visible; everyone done with Bs[cur]
  }
  // epilogue: C[row][col]: col = lane&15, row = (lane>>4)*4 + reg
#pragma unroll
  for (int mf = 0; mf < 2; ++mf)
#pragma unroll
    for (int nf = 0; nf < 4; ++nf)
#pragma unroll
      for (int r = 0; r < 4; ++r) {
        int row = w * 32 + mf * 16 + h * 4 + r;
        int col = n0 + nf * 16 + c;
        float v = acc[mf][nf][r];
        if (v > sthr[row]) {
          int p = atomicAdd(&gcnt[row], 1);
          if (p < SURV_CAP) gcand[(size_t)row * SURV_CAP + p] = make_uint2(__float_as_uint(v), (unsigned)col);
        }
      }
}

// ------- Kernel D: per-mention select top-200: sort survivors by f32 sims,
//         f64-rescore top RESC, exact sort, emit in sims-desc order -------
__global__ __launch_bounds__(256) void k_select(
    const uint2* __restrict__ gcand, const int* __restrict__ gcnt,
    const float* __restrict__ kb, const double* __restrict__ q64,
    int* __restrict__ cidx) {
  int m = blockIdx.x;
  __shared__ float skf[SURV_CAP];
  __shared__ int   sidx[SURV_CAP];
  __shared__ double sq[DD];
  __shared__ double skey[256];
  __shared__ int    skidx[256];
  int tid = threadIdx.x;
  int cnt = gcnt[m]; if (cnt > SURV_CAP) cnt = SURV_CAP;
  for (int d = tid; d < DD; d += 256) sq[d] = q64[(size_t)m * DD + d];
  for (int i = tid; i < SURV_CAP; i += 256) {
    if (i < cnt) {
      uint2 v = gcand[(size_t)m * SURV_CAP + i];
      skf[i] = __uint_as_float(v.x);
      sidx[i] = (int)v.y;
    } else { skf[i] = -FLT_MAX; sidx[i] = 0x7fffffff; }
  }
  __syncthreads();
  for (int k = 2; k <= SURV_CAP; k <<= 1) {
    for (int j = k >> 1; j > 0; j >>= 1) {
      for (int i = tid; i < SURV_CAP; i += 256) {
        int l = i ^ j;
        if (l > i) {
          float ka = skf[i], kb2 = skf[l];
          int ia = sidx[i], ib = sidx[l];
          bool lBefore = (kb2 > ka) || (kb2 == ka && ib < ia);
          bool iBefore = (ka > kb2) || (ka == kb2 && ia < ib);
          bool dir = ((i & k) == 0);
          bool sw = dir ? lBefore : iBefore;
          if (sw) { skf[i] = kb2; skf[l] = ka; sidx[i] = ib; sidx[l] = ia; }
        }
      }
      __syncthreads();
    }
  }
  int lane = tid & 63, wv = tid >> 6;
  for (int cpos = wv; cpos < RESC; cpos += 4) {
    int ci = sidx[cpos];
    double s;
    if (ci < NKB) {
      const float* krow = kb + (size_t)ci * DD;
      double acc = 0.0;
      for (int d = lane; d < DD; d += 64) acc += sq[d] * (double)krow[d];
      for (int off2 = 32; off2 > 0; off2 >>= 1) acc += __shfl_down(acc, off2, 64);
      s = acc;
    } else s = -INFINITY;
    if (lane == 0) { skey[cpos] = s; skidx[cpos] = ci; }
  }
  if (tid >= RESC && tid < 256) { skey[tid] = -INFINITY; skidx[tid] = 0x7fffffff; }
  __syncthreads();
  for (int k = 2; k <= 256; k <<= 1) {
    for (int j = k >> 1; j > 0; j >>= 1) {
      int i = tid, l = i ^ j;
      if (l > i) {
        double ka = skey[i], kb2 = skey[l];
        int ia = skidx[i], ib = skidx[l];
        bool lBefore = (kb2 > ka) || (kb2 == ka && ib < ia);
        bool iBefore = (ka > kb2) || (ka == kb2 && ia < ib);
        bool dir = ((i & k) == 0);
        bool sw = dir ? lBefore : iBefore;
        if (sw) { skey[i] = kb2; skey[l] = ka; skidx[i] = ib; skidx[l] = ia; }
      }
      __syncthreads();
    }
  }
  for (int cc = tid; cc < KK; cc += 256) {
    int v = skidx[cc];
    cidx[(size_t)m * KK + cc] = (v < NKB) ? v : 0;
  }
}

// ------- Kernel PS: pre-split candidate rows into bf16 hi/lo planes (once, coalesced) -------
// Ahg/Alg layout [MM*KK][DD] bf16 — score2's A-stage becomes pure uint4 copies.
__global__ __launch_bounds__(256) void k_presplit(
    const float* __restrict__ kb, const int* __restrict__ cidx,
    unsigned short* __restrict__ Ahg, unsigned short* __restrict__ Alg) {
  int base = blockIdx.x * 8;
  int tid = threadIdx.x;
  int lr = tid >> 5, t = tid & 31;
  int row = cidx[base + lr];
  const float* src = kb + (size_t)row * DD;
  unsigned short* dh = Ahg + (size_t)(base + lr) * DD;
  unsigned short* dl = Alg + (size_t)(base + lr) * DD;
  for (int i = t; i < DD / 4; i += 32) {
    float4 v = *(const float4*)(src + i * 4);
    unsigned short h0, h1, h2, h3, l0, l1, l2, l3;
    splitbf(v.x, h0, l0); splitbf(v.y, h1, l1);
    splitbf(v.z, h2, l2); splitbf(v.w, h3, l3);
    uint2 ph, pl;
    ph.x = (unsigned)h0 | ((unsigned)h1 << 16); ph.y = (unsigned)h2 | ((unsigned)h3 << 16);
    pl.x = (unsigned)l0 | ((unsigned)l1 << 16); pl.y = (unsigned)l2 | ((unsigned)l3 << 16);
    *(uint2*)(dh + i * 4) = ph;
    *(uint2*)(dl + i * 4) = pl;
  }
}

// ------- Kernel E v5: scorer GEMM partials — LDS-staged from PRE-SPLIT planes (no splitbf
// in hot loop) + T14 reg-prefetch. Same swizzle, same MFMA order -> bit-identical z.
__global__ __launch_bounds__(256) void k_score2(
    const unsigned short* __restrict__ Ahg, const unsigned short* __restrict__ Alg,
    const float* __restrict__ mp32, const unsigned short* __restrict__ Bth,
    const unsigned short* __restrict__ Btl, const float* __restrict__ bs1,
    const float* __restrict__ Ws2, float* __restrict__ gpart) {
  __shared__ unsigned short Ah[256 * 32], Al[256 * 32];   // 16 KB each, swizzled
  __shared__ unsigned short Bh[64 * 32], Bl[64 * 32];     // 4 KB each, swizzled
  __shared__ float smp[3][64], sb1v[64], sw2v[64];
  int p = blockIdx.x;
  int x = p & 7, j = p >> 3;
  int ct = x + 8 * (j / NET), et = j % NET;
  int r0 = ct * 256, e0 = et * 64;
  int tid = threadIdx.x, lane = tid & 63, w = tid >> 6;
  int h = lane >> 4, c = lane & 15;
  int m0 = r0 / KK;
  int mm1 = (m0 + 1 < MM) ? m0 + 1 : MM - 1;
  int mm2 = (m0 + 2 < MM) ? m0 + 2 : MM - 1;
  if (tid < 64) {
    smp[0][tid] = mp32[(size_t)m0 * DD + e0 + tid];
    smp[1][tid] = mp32[(size_t)mm1 * DD + e0 + tid];
    smp[2][tid] = mp32[(size_t)mm2 * DD + e0 + tid];
    sb1v[tid] = bs1[e0 + tid];
    sw2v[tid] = Ws2[e0 + tid];
  }
  // per-thread staging addresses: A idx = tid + it*256 -> rr = idx>>2, k8 = idx&3
  const unsigned short* ahaddr[4];
  const unsigned short* aladdr[4];
#pragma unroll
  for (int it = 0; it < 4; ++it) {
    int idx = tid + it * 256;
    int rr = idx >> 2, k8 = idx & 3;
    ahaddr[it] = Ahg + (size_t)(r0 + rr) * DD + k8 * 8;
    aladdr[it] = Alg + (size_t)(r0 + rr) * DD + k8 * 8;
  }
  const int be = tid >> 2, bk8 = tid & 3;
  const unsigned short* bhaddr = Bth + (size_t)(e0 + be) * DD + bk8 * 8;
  const unsigned short* bladdr = Btl + (size_t)(e0 + be) * DD + bk8 * 8;
  uint4 pah[4], pal[4], pbh, pbl;
#pragma unroll
  for (int it = 0; it < 4; ++it) {
    pah[it] = *(const uint4*)(ahaddr[it]);
    pal[it] = *(const uint4*)(aladdr[it]);
  }
  pbh = *(const uint4*)(bhaddr);
  pbl = *(const uint4*)(bladdr);
  f32x4 acc[4][4] = {};
  for (int k0 = 0; k0 < DD; k0 += 32) {
    __syncthreads();   // prev MFMA done reading LDS (also covers smp staging at k0=0)
#pragma unroll
    for (int it = 0; it < 4; ++it) {
      int idx = tid + it * 256;
      int rr = idx >> 2, k8 = idx & 3;
      int off = (rr * 64 + k8 * 16) ^ ((rr & 7) << 4);
      *(uint4*)((char*)Ah + off) = pah[it];
      *(uint4*)((char*)Al + off) = pal[it];
    }
    {
      int off = (be * 64 + bk8 * 16) ^ ((be & 7) << 4);
      *(uint4*)((char*)Bh + off) = pbh;
      *(uint4*)((char*)Bl + off) = pbl;
    }
    if (k0 + 32 < DD) {
#pragma unroll
      for (int it = 0; it < 4; ++it) {
        pah[it] = *(const uint4*)(ahaddr[it] + k0 + 32);
        pal[it] = *(const uint4*)(aladdr[it] + k0 + 32);
      }
      pbh = *(const uint4*)(bhaddr + k0 + 32);
      pbl = *(const uint4*)(bladdr + k0 + 32);
    }
    __syncthreads();   // LDS ready
    bf16x8 ah[4], al[4];
#pragma unroll
    for (int mf = 0; mf < 4; ++mf) {
      int rr = w * 64 + mf * 16 + c;
      int off = (rr * 64 + h * 16) ^ ((rr & 7) << 4);
      ah[mf] = *(bf16x8*)((char*)Ah + off);
      al[mf] = *(bf16x8*)((char*)Al + off);
    }
#pragma unroll
    for (int nf = 0; nf < 4; ++nf) {
      int e = nf * 16 + c;
      int off = (e * 64 + h * 16) ^ ((e & 7) << 4);
      bf16x8 bh = *(bf16x8*)((char*)Bh + off);
      bf16x8 bl = *(bf16x8*)((char*)Bl + off);
#pragma unroll
      for (int mf = 0; mf < 4; ++mf) {
        acc[mf][nf] = __builtin_amdgcn_mfma_f32_16x16x32_bf16(ah[mf], bh, acc[mf][nf], 0, 0, 0);
        acc[mf][nf] = __builtin_amdgcn_mfma_f32_16x16x32_bf16(ah[mf], bl, acc[mf][nf], 0, 0, 0);
        acc[mf][nf] = __builtin_amdgcn_mfma_f32_16x16x32_bf16(al[mf], bh, acc[mf][nf], 0, 0, 0);
      }
    }
  }
  int bnd1 = (m0 + 1) * KK, bnd2 = (m0 + 2) * KK;
#pragma unroll
  for (int mf = 0; mf < 4; ++mf) {
    float zp[4] = {0.f, 0.f, 0.f, 0.f};
#pragma unroll
    for (int nf = 0; nf < 4; ++nf) {
      int el = nf * 16 + c;
      float b1v = sb1v[el], w2v = sw2v[el];
#pragma unroll
      for (int r = 0; r < 4; ++r) {
        int rowg = r0 + w * 64 + mf * 16 + h * 4 + r;
        int sel = (rowg >= bnd1) + (rowg >= bnd2);
        float hh = acc[mf][nf][r] + smp[sel][el] + b1v;
        if (hh > 0.f) zp[r] += hh * w2v;
      }
    }
#pragma unroll
    for (int r = 0; r < 4; ++r) {
      float v = zp[r];
      v += __shfl_xor(v, 1, 64);
      v += __shfl_xor(v, 2, 64);
      v += __shfl_xor(v, 4, 64);
      v += __shfl_xor(v, 8, 64);
      if (c == 0)
        gpart[(size_t)(r0 + w * 64 + mf * 16 + h * 4 + r) * NET + et] = v;
    }
  }
}

// ------- Kernel E2: fused zred + mark (z = f64 sum of 12 partials + bs2; then sort, mark) -------
__global__ __launch_bounds__(256) void k_mark(
    const float* __restrict__ gpart, const float* __restrict__ bs2,
    double* __restrict__ z64, int* __restrict__ marks, int* __restrict__ mcnt) {
  int m = blockIdx.x;
  __shared__ double sk[256];
  __shared__ int sp[256];
  __shared__ int flag[256];
  int tid = threadIdx.x;
  flag[tid] = 0;
  if (tid < KK) {
    double s = 0.0;
#pragma unroll
    for (int i = 0; i < NET; ++i) s += (double)gpart[(size_t)(m * KK + tid) * NET + i];
    s += (double)bs2[0];
    z64[(size_t)m * KK + tid] = s;
    sk[tid] = s; sp[tid] = tid;
  } else { sk[tid] = -INFINITY; sp[tid] = 0x7fffffff; }
  __syncthreads();
  for (int k = 2; k <= 256; k <<= 1) {
    for (int j = k >> 1; j > 0; j >>= 1) {
      int i = tid, l = i ^ j;
      if (l > i) {
        double ka = sk[i], kb2 = sk[l];
        int ia = sp[i], ib = sp[l];
        bool lBefore = (kb2 > ka) || (kb2 == ka && ib < ia);
        bool iBefore = (ka > kb2) || (ka == kb2 && ia < ib);
        bool dir = ((i & k) == 0);
        bool sw = dir ? lBefore : iBefore;
        if (sw) { sk[i] = kb2; sk[l] = ka; sp[i] = ib; sp[l] = ia; }
      }
      __syncthreads();
    }
  }
  if (tid <= 120) {
    if (sk[tid] - sk[tid + 1] < DELTA) {
      flag[tid] = 1;
      atomicExch(&flag[tid + 1], 1);
    }
  }
  __syncthreads();
  if (tid <= 121 && flag[tid]) {
    int p = atomicAdd(mcnt, 1);
    if (p < MAXMARK) marks[p] = m * KK + sp[tid];
  }
}

// ------- Kernel E3: exact f64 rescore of marked candidates (in-place into z64) -------
__global__ __launch_bounds__(256) void k_rescore(
    const float* __restrict__ kb, const int* __restrict__ cidx,
    const double* __restrict__ mp64, const float* __restrict__ Ws1,
    const float* __restrict__ bs1, const float* __restrict__ Ws2,
    const float* __restrict__ bs2, const int* __restrict__ marks,
    const int* __restrict__ mcnt, double* __restrict__ z64) {
  int cnt = *mcnt; if (cnt > MAXMARK) cnt = MAXMARK;
  __shared__ float sc[DD];
  __shared__ double sred[256];
  int tid = threadIdx.x;
  for (int it = blockIdx.x; it < cnt; it += gridDim.x) {
    int r = marks[it];
    int m = r / KK;
    int row = cidx[r];
    for (int d = tid; d < DD; d += 256) sc[d] = kb[(size_t)row * DD + d];
    __syncthreads();
    double pz = 0.0;
    for (int e = tid; e < DD; e += 256) {
      double a = 0.0;
      for (int d = 0; d < DD; ++d) a += (double)sc[d] * (double)Ws1[(size_t)(DD + d) * DD + e];
      double hv = mp64[(size_t)m * DD + e] + a + (double)bs1[e];
      if (hv > 0) pz += hv * (double)Ws2[e];
    }
    sred[tid] = pz; __syncthreads();
    for (int s = 128; s > 0; s >>= 1) { if (tid < s) sred[tid] += sred[tid + s]; __syncthreads(); }
    if (tid == 0) z64[r] = sred[0] + (double)bs2[0];
    __syncthreads();
  }
}

// ---------------- Kernel F: per-mention top-100 of 200 (bitonic 256) ----------------
__global__ __launch_bounds__(256) void k_final(
    const double* __restrict__ z64, const int* __restrict__ cidx, float* __restrict__ out) {
  int m = blockIdx.x;
  __shared__ double sk[256];
  __shared__ int sp[256];
  int tid = threadIdx.x;
  if (tid < KK) { sk[tid] = z64[(size_t)m * KK + tid]; sp[tid] = tid; }
  else { sk[tid] = -INFINITY; sp[tid] = 0x7fffffff; }
  __syncthreads();
  for (int k = 2; k <= 256; k <<= 1) {
    for (int j = k >> 1; j > 0; j >>= 1) {
      int i = tid, l = i ^ j;
      if (l > i) {
        double ka = sk[i], kb2 = sk[l];
        int ia = sp[i], ib = sp[l];
        bool lBefore = (kb2 > ka) || (kb2 == ka && ib < ia);
        bool iBefore = (ka > kb2) || (ka == kb2 && ia < ib);
        bool dir = ((i & k) == 0);
        bool sw = dir ? lBefore : iBefore;
        if (sw) { sk[i] = kb2; sk[l] = ka; sp[i] = ib; sp[l] = ia; }
      }
      __syncthreads();
    }
  }
  if (tid < TOPK) {
    double z = sk[tid];
    out[(size_t)m * TOPK + tid] = (float)(1.0 / (1.0 + exp(-z)));
    out[(size_t)MM * TOPK + (size_t)m * TOPK + tid] = (float)cidx[(size_t)m * KK + sp[tid]];
  }
}

// ---------------- host ----------------
extern "C" void kernel_launch(void* const* d_in, const int* in_sizes, int n_in,
                              void* d_out, int out_size, void* d_ws, size_t ws_size,
                              hipStream_t stream) {
  const float* text  = (const float*)d_in[0];
  const float* kb    = (const float*)d_in[1];
  const float* Wret  = (const float*)d_in[2];
  const float* bret  = (const float*)d_in[3];
  const float* Ws1   = (const float*)d_in[4];
  const float* bs1   = (const float*)d_in[5];
  const float* Ws2   = (const float*)d_in[6];
  const float* bs2   = (const float*)d_in[7];
  const int* msent   = (const int*)d_in[8];
  const int* mstart  = (const int*)d_in[9];
  const int* mlen    = (const int*)d_in[10];
  float* out = (float*)d_out;

  char* ws = (char*)d_ws;
  size_t off = 0;
  auto alloc = [&](size_t bytes) -> void* {
    void* p = ws + off;
    off = (off + bytes + 255) & ~(size_t)255;
    return p;
  };
  double* q64  = (double*)alloc((size_t)MM * DD * 8);
  unsigned short* qb16 = (unsigned short*)alloc((size_t)MM * DD * 2);
  float*  tthr = (float*) alloc((size_t)MM * 4);
  double* mp64 = (double*)alloc((size_t)MM * DD * 8);
  float*  mp32 = (float*) alloc((size_t)MM * DD * 4);
  int*    cidx = (int*)   alloc((size_t)MM * KK * 4);
  double* z64  = (double*)alloc((size_t)MM * KK * 8);
  float*  gpart = (float*)alloc((size_t)MM * KK * NET * 4);
  int*    marks = (int*)  alloc((size_t)MAXMARK * 4);
  int*    mcnt  = (int*)  alloc(256);
  int*    gcnt  = (int*)  alloc((size_t)MM * 4);
  uint2*  gcand = (uint2*)alloc((size_t)MM * SURV_CAP * 8);
  unsigned short* Bth = (unsigned short*)alloc((size_t)DD * DD * 2);
  unsigned short* Btl = (unsigned short*)alloc((size_t)DD * DD * 2);
  float*  WretT = (float*)alloc((size_t)DD * DD * 4);
  unsigned short* Ahg = (unsigned short*)alloc((size_t)MM * KK * DD * 2);
  unsigned short* Alg = (unsigned short*)alloc((size_t)MM * KK * DD * 2);
  (void)ws_size;

  dim3 gt(DD / 64, DD / 64);
  k_prepT<<<gt, 256, 0, stream>>>(Wret, WretT);
  k_prep<<<DD, 256, 0, stream>>>(Ws1, Bth, Btl);
  k_front<<<MM, 256, 0, stream>>>(text, msent, mstart, mlen, WretT, bret, Ws1,
                                  q64, qb16, tthr, mp64, mp32);

  hipMemsetAsync(gcnt, 0, (size_t)MM * 4, stream);
  k_sims_mfma<<<NKB / 64, 512, 0, stream>>>(qb16, kb, tthr, gcnt, gcand);
  k_select<<<MM, 256, 0, stream>>>(gcand, gcnt, kb, q64, cidx);

  k_presplit<<<(MM * KK) / 8, 256, 0, stream>>>(kb, cidx, Ahg, Alg);
  k_score2<<<(MM * KK / 256) * NET, 256, 0, stream>>>(Ahg, Alg, mp32, Bth, Btl, bs1, Ws2, gpart);
  hipMemsetAsync(mcnt, 0, 4, stream);
  k_mark<<<MM, 256, 0, stream>>>(gpart, bs2, z64, marks, mcnt);
  k_rescore<<<2048, 256, 0, stream>>>(kb, cidx, mp64, Ws1, bs1, Ws2, bs2, marks, mcnt, z64);
  k_final<<<MM, 256, 0, stream>>>(z64, cidx, out);
}

// Round 17
// 1306.794 us; speedup vs baseline: 1.3473x; 1.3473x over previous
//
#include <hip/hip_runtime.h>
#include <cfloat>
#include <cmath>
#include <cstdint>

#define DD 768
#define MM 256
#define NKB 200000
#define SLEN 512
#define KK 200      // 2*top_k
#define TOPK 100
#define SURV_CAP 1024
#define RESC 232
#define THRC 2.70f
#define MAXMARK 32768
#define DELTA 4e-5
#define NET 12      // e-tiles of 64

typedef __attribute__((ext_vector_type(8))) short bf16x8;
typedef __attribute__((ext_vector_type(4))) float f32x4;

__device__ __forceinline__ unsigned short f2bf_rne(float x) {
  unsigned u = __float_as_uint(x);
  unsigned r = (u + 0x7FFFu + ((u >> 16) & 1u)) >> 16;
  return (unsigned short)r;
}
__device__ __forceinline__ float bf2f(unsigned short us) {
  return __uint_as_float(((unsigned)us) << 16);
}
__device__ __forceinline__ void splitbf(float x, unsigned short& hi, unsigned short& lo) {
  hi = f2bf_rne(x);
  lo = f2bf_rne(x - bf2f(hi));
}

// ---------------- Kernel PT: WretT[d][e] = Wret[e][d] (LDS-tiled, coalesced both sides) ----------------
__global__ __launch_bounds__(256) void k_prepT(
    const float* __restrict__ Wret, float* __restrict__ WretT) {
  __shared__ float tile[64][65];
  int e0 = blockIdx.x * 64, d0 = blockIdx.y * 64;
  int tid = threadIdx.x;
  int r = tid >> 6, cc = tid & 63;
  for (int i = 0; i < 64; i += 4)
    tile[r + i][cc] = Wret[(size_t)(e0 + r + i) * DD + d0 + cc];
  __syncthreads();
  for (int i = 0; i < 64; i += 4)
    WretT[(size_t)(d0 + r + i) * DD + e0 + cc] = tile[cc][r + i];
}

// ------- Kernel FRONT: fused mention-mean + query (via WretT, coalesced) + m_part -------
__global__ __launch_bounds__(256) void k_front(
    const float* __restrict__ text, const int* __restrict__ msent,
    const int* __restrict__ mstart, const int* __restrict__ mlen,
    const float* __restrict__ WretT, const float* __restrict__ bret,
    const float* __restrict__ Ws1,
    double* __restrict__ q64, unsigned short* __restrict__ qb16,
    float* __restrict__ tthr, double* __restrict__ mp64,
    float* __restrict__ mp32) {
  int m = blockIdx.x;
  __shared__ double sme[DD];
  __shared__ float snorm[256];
  int tid = threadIdx.x;
  {
    int sent = msent[m], st = mstart[m], ln = mlen[m];
    const float* base = text + (size_t)sent * SLEN * DD;
    for (int d = tid; d < DD; d += 256) {
      double acc = 0.0;
      for (int s = st; s <= st + ln; ++s) acc += (double)base[(size_t)s * DD + d];
      sme[d] = acc / (double)(ln + 1);
    }
  }
  __syncthreads();
  float nloc = 0.f;
  for (int e = tid; e < DD; e += 256) {
    double aq = (double)bret[e];
    double amp = 0.0;
    for (int d = 0; d < DD; ++d) {
      double md = sme[d];
      aq  += md * (double)WretT[(size_t)d * DD + e];
      amp += md * (double)Ws1[(size_t)d * DD + e];
    }
    q64[(size_t)m * DD + e] = aq;
    qb16[(size_t)m * DD + e] = f2bf_rne((float)aq);
    mp64[(size_t)m * DD + e] = amp;
    mp32[(size_t)m * DD + e] = (float)amp;
    nloc += (float)(aq * aq);
  }
  snorm[tid] = nloc; __syncthreads();
  for (int s = 128; s > 0; s >>= 1) {
    if (tid < s) snorm[tid] += snorm[tid + s];
    __syncthreads();
  }
  if (tid == 0) tthr[m] = THRC * sqrtf(snorm[0]);
}

// ---------------- Kernel P: split+transpose Ws1[D:] -> Bt_hi/Bt_lo [e][k] bf16 ----------------
__global__ __launch_bounds__(256) void k_prep(
    const float* __restrict__ Ws1, unsigned short* __restrict__ Bth,
    unsigned short* __restrict__ Btl) {
  int e = blockIdx.x;
  for (int k = threadIdx.x; k < DD; k += 256) {
    float x = Ws1[(size_t)(DD + k) * DD + e];
    unsigned short hi, lo;
    splitbf(x, hi, lo);
    Bth[(size_t)e * DD + k] = hi;
    Btl[(size_t)e * DD + k] = lo;
  }
}

// ------- Kernel C v4: sims = q @ kb^T via bf16 MFMA; double-buffered B LDS,
// ONE barrier per 32-k step, 3-deep B prefetch, 1-deep A prefetch. Same MFMA order.
__global__ __launch_bounds__(512) void k_sims_mfma(
    const unsigned short* __restrict__ qb, const float* __restrict__ kb,
    const float* __restrict__ tthr, int* __restrict__ gcnt,
    uint2* __restrict__ gcand) {
  __shared__ unsigned short Bs[2][64 * 32];   // 8 KB, swizzled, double-buffered
  __shared__ float sthr[256];
  int n0 = blockIdx.x * 64;
  int tid = threadIdx.x;
  int lane = tid & 63, w = tid >> 6;       // 8 waves
  int h = lane >> 4, c = lane & 15;
  if (tid < 256) sthr[tid] = tthr[tid];
  f32x4 acc[2][4] = {};
  const int brow = n0 + (tid >> 3);        // stage row (64 rows x 8 thr/row)
  const int bk4  = (tid & 7) * 4;          // 4 f32 per thread
  const int bwoff = ((tid >> 3) * 64 + (tid & 7) * 8) ^ (((tid >> 3) & 7) << 4);
  auto ldB = [&](int k0) -> float4 {
    return *(const float4*)(kb + (size_t)brow * DD + k0 + bk4);
  };
  auto stB = [&](int buf, const float4 &v) {
    uint2 p;
    p.x = (unsigned)f2bf_rne(v.x) | ((unsigned)f2bf_rne(v.y) << 16);
    p.y = (unsigned)f2bf_rne(v.z) | ((unsigned)f2bf_rne(v.w) << 16);
    *(uint2*)((char*)Bs + buf * 4096 + bwoff) = p;
  };
  const unsigned short* qa0 = qb + (size_t)(w * 32 + c) * DD;
  const unsigned short* qa1 = qb + (size_t)(w * 32 + 16 + c) * DD;
  // prologue: buf0 = step0; pend1 = step1 data, pend2 = step2 data
  stB(0, ldB(0));
  float4 pend1 = ldB(32);
  float4 pend2 = ldB(64);
  bf16x8 a0 = *(const bf16x8*)(qa0 + h * 8);
  bf16x8 a1 = *(const bf16x8*)(qa1 + h * 8);
  __syncthreads();
#pragma unroll
  for (int s = 0; s < 24; ++s) {
    int cur = s & 1;
    if (s + 1 < 24) stB(cur ^ 1, pend1);     // write next buffer (prev consumers done at last barrier)
    pend1 = pend2;
    if (s + 3 < 24) pend2 = ldB((s + 3) * 32);
    int kn = (s + 1 < 24) ? (s + 1) * 32 : s * 32;
    bf16x8 a0n = *(const bf16x8*)(qa0 + kn + h * 8);   // prefetch next A (L2-hot)
    bf16x8 a1n = *(const bf16x8*)(qa1 + kn + h * 8);
#pragma unroll
    for (int nf = 0; nf < 4; ++nf) {
      int n = nf * 16 + c;
      int off = (n * 64 + h * 16) ^ ((n & 7) << 4);
      bf16x8 b = *(bf16x8*)((char*)Bs + cur * 4096 + off);
      acc[0][nf] = __builtin_amdgcn_mfma_f32_16x16x32_bf16(a0, b, acc[0][nf], 0, 0, 0);
      acc[1][nf] = __builtin_amdgcn_mfma_f32_16x16x32_bf16(a1, b, acc[1][nf], 0, 0, 0);
    }
    a0 = a0n; a1 = a1n;
    __syncthreads();   // next buffer visible; everyone done with Bs[cur]
  }
  // epilogue: C[row][col]: col = lane&15, row = (lane>>4)*4 + reg
#pragma unroll
  for (int mf = 0; mf < 2; ++mf)
#pragma unroll
    for (int nf = 0; nf < 4; ++nf)
#pragma unroll
      for (int r = 0; r < 4; ++r) {
        int row = w * 32 + mf * 16 + h * 4 + r;
        int col = n0 + nf * 16 + c;
        float v = acc[mf][nf][r];
        if (v > sthr[row]) {
          int p = atomicAdd(&gcnt[row], 1);
          if (p < SURV_CAP) gcand[(size_t)row * SURV_CAP + p] = make_uint2(__float_as_uint(v), (unsigned)col);
        }
      }
}

// ------- Kernel D: per-mention select top-200: sort survivors by f32 sims,
//         f64-rescore top RESC, exact sort, emit in sims-desc order -------
__global__ __launch_bounds__(256) void k_select(
    const uint2* __restrict__ gcand, const int* __restrict__ gcnt,
    const float* __restrict__ kb, const double* __restrict__ q64,
    int* __restrict__ cidx) {
  int m = blockIdx.x;
  __shared__ float skf[SURV_CAP];
  __shared__ int   sidx[SURV_CAP];
  __shared__ double sq[DD];
  __shared__ double skey[256];
  __shared__ int    skidx[256];
  int tid = threadIdx.x;
  int cnt = gcnt[m]; if (cnt > SURV_CAP) cnt = SURV_CAP;
  for (int d = tid; d < DD; d += 256) sq[d] = q64[(size_t)m * DD + d];
  for (int i = tid; i < SURV_CAP; i += 256) {
    if (i < cnt) {
      uint2 v = gcand[(size_t)m * SURV_CAP + i];
      skf[i] = __uint_as_float(v.x);
      sidx[i] = (int)v.y;
    } else { skf[i] = -FLT_MAX; sidx[i] = 0x7fffffff; }
  }
  __syncthreads();
  for (int k = 2; k <= SURV_CAP; k <<= 1) {
    for (int j = k >> 1; j > 0; j >>= 1) {
      for (int i = tid; i < SURV_CAP; i += 256) {
        int l = i ^ j;
        if (l > i) {
          float ka = skf[i], kb2 = skf[l];
          int ia = sidx[i], ib = sidx[l];
          bool lBefore = (kb2 > ka) || (kb2 == ka && ib < ia);
          bool iBefore = (ka > kb2) || (ka == kb2 && ia < ib);
          bool dir = ((i & k) == 0);
          bool sw = dir ? lBefore : iBefore;
          if (sw) { skf[i] = kb2; skf[l] = ka; sidx[i] = ib; sidx[l] = ia; }
        }
      }
      __syncthreads();
    }
  }
  int lane = tid & 63, wv = tid >> 6;
  for (int cpos = wv; cpos < RESC; cpos += 4) {
    int ci = sidx[cpos];
    double s;
    if (ci < NKB) {
      const float* krow = kb + (size_t)ci * DD;
      double acc = 0.0;
      for (int d = lane; d < DD; d += 64) acc += sq[d] * (double)krow[d];
      for (int off2 = 32; off2 > 0; off2 >>= 1) acc += __shfl_down(acc, off2, 64);
      s = acc;
    } else s = -INFINITY;
    if (lane == 0) { skey[cpos] = s; skidx[cpos] = ci; }
  }
  if (tid >= RESC && tid < 256) { skey[tid] = -INFINITY; skidx[tid] = 0x7fffffff; }
  __syncthreads();
  for (int k = 2; k <= 256; k <<= 1) {
    for (int j = k >> 1; j > 0; j >>= 1) {
      int i = tid, l = i ^ j;
      if (l > i) {
        double ka = skey[i], kb2 = skey[l];
        int ia = skidx[i], ib = skidx[l];
        bool lBefore = (kb2 > ka) || (kb2 == ka && ib < ia);
        bool iBefore = (ka > kb2) || (ka == kb2 && ia < ib);
        bool dir = ((i & k) == 0);
        bool sw = dir ? lBefore : iBefore;
        if (sw) { skey[i] = kb2; skey[l] = ka; skidx[i] = ib; skidx[l] = ia; }
      }
      __syncthreads();
    }
  }
  for (int cc = tid; cc < KK; cc += 256) {
    int v = skidx[cc];
    cidx[(size_t)m * KK + cc] = (v < NKB) ? v : 0;
  }
}

// ------- Kernel E v4 (restored): scorer GEMM partials — LDS-staged + T14 reg-prefetch -------
__global__ __launch_bounds__(256) void k_score2(
    const float* __restrict__ kb, const int* __restrict__ cidx,
    const float* __restrict__ mp32, const unsigned short* __restrict__ Bth,
    const unsigned short* __restrict__ Btl, const float* __restrict__ bs1,
    const float* __restrict__ Ws2, float* __restrict__ gpart) {
  __shared__ unsigned short Ah[256 * 32], Al[256 * 32];   // 16 KB each, swizzled
  __shared__ unsigned short Bh[64 * 32], Bl[64 * 32];     // 4 KB each, swizzled
  __shared__ float smp[3][64], sb1v[64], sw2v[64];
  __shared__ int srow[256];
  int p = blockIdx.x;
  int x = p & 7, j = p >> 3;
  int ct = x + 8 * (j / NET), et = j % NET;
  int r0 = ct * 256, e0 = et * 64;
  int tid = threadIdx.x, lane = tid & 63, w = tid >> 6;
  int h = lane >> 4, c = lane & 15;
  srow[tid] = cidx[r0 + tid];
  int m0 = r0 / KK;
  int mm1 = (m0 + 1 < MM) ? m0 + 1 : MM - 1;
  int mm2 = (m0 + 2 < MM) ? m0 + 2 : MM - 1;
  if (tid < 64) {
    smp[0][tid] = mp32[(size_t)m0 * DD + e0 + tid];
    smp[1][tid] = mp32[(size_t)mm1 * DD + e0 + tid];
    smp[2][tid] = mp32[(size_t)mm2 * DD + e0 + tid];
    sb1v[tid] = bs1[e0 + tid];
    sw2v[tid] = Ws2[e0 + tid];
  }
  __syncthreads();   // srow staged (needed for A addresses)
  const float* aaddr[8];
#pragma unroll
  for (int it = 0; it < 8; ++it) {
    int idx = tid + it * 256;
    int rr = idx >> 3, f4 = idx & 7;
    aaddr[it] = kb + (size_t)srow[rr] * DD + f4 * 4;
  }
  const int be = tid >> 2, bk8 = tid & 3;
  const unsigned short* bhaddr = Bth + (size_t)(e0 + be) * DD + bk8 * 8;
  const unsigned short* bladdr = Btl + (size_t)(e0 + be) * DD + bk8 * 8;
  float4 pa[8];
  uint4 pbh, pbl;
#pragma unroll
  for (int it = 0; it < 8; ++it) pa[it] = *(const float4*)(aaddr[it]);
  pbh = *(const uint4*)(bhaddr);
  pbl = *(const uint4*)(bladdr);
  f32x4 acc[4][4] = {};
  for (int k0 = 0; k0 < DD; k0 += 32) {
    __syncthreads();   // prev MFMA done reading LDS
#pragma unroll
    for (int it = 0; it < 8; ++it) {
      int idx = tid + it * 256;
      int rr = idx >> 3, f4 = idx & 7;
      float4 v = pa[it];
      unsigned short h0, h1, h2, h3, l0, l1, l2, l3;
      splitbf(v.x, h0, l0); splitbf(v.y, h1, l1);
      splitbf(v.z, h2, l2); splitbf(v.w, h3, l3);
      uint2 ph, pl;
      ph.x = (unsigned)h0 | ((unsigned)h1 << 16); ph.y = (unsigned)h2 | ((unsigned)h3 << 16);
      pl.x = (unsigned)l0 | ((unsigned)l1 << 16); pl.y = (unsigned)l2 | ((unsigned)l3 << 16);
      int off = (rr * 64 + f4 * 8) ^ ((rr & 7) << 4);
      *(uint2*)((char*)Ah + off) = ph;
      *(uint2*)((char*)Al + off) = pl;
    }
    {
      int off = (be * 64 + bk8 * 16) ^ ((be & 7) << 4);
      *(uint4*)((char*)Bh + off) = pbh;
      *(uint4*)((char*)Bl + off) = pbl;
    }
    if (k0 + 32 < DD) {
#pragma unroll
      for (int it = 0; it < 8; ++it) pa[it] = *(const float4*)(aaddr[it] + k0 + 32);
      pbh = *(const uint4*)(bhaddr + k0 + 32);
      pbl = *(const uint4*)(bladdr + k0 + 32);
    }
    __syncthreads();   // LDS ready
    bf16x8 ah[4], al[4];
#pragma unroll
    for (int mf = 0; mf < 4; ++mf) {
      int rr = w * 64 + mf * 16 + c;
      int off = (rr * 64 + h * 16) ^ ((rr & 7) << 4);
      ah[mf] = *(bf16x8*)((char*)Ah + off);
      al[mf] = *(bf16x8*)((char*)Al + off);
    }
#pragma unroll
    for (int nf = 0; nf < 4; ++nf) {
      int e = nf * 16 + c;
      int off = (e * 64 + h * 16) ^ ((e & 7) << 4);
      bf16x8 bh = *(bf16x8*)((char*)Bh + off);
      bf16x8 bl = *(bf16x8*)((char*)Bl + off);
#pragma unroll
      for (int mf = 0; mf < 4; ++mf) {
        acc[mf][nf] = __builtin_amdgcn_mfma_f32_16x16x32_bf16(ah[mf], bh, acc[mf][nf], 0, 0, 0);
        acc[mf][nf] = __builtin_amdgcn_mfma_f32_16x16x32_bf16(ah[mf], bl, acc[mf][nf], 0, 0, 0);
        acc[mf][nf] = __builtin_amdgcn_mfma_f32_16x16x32_bf16(al[mf], bh, acc[mf][nf], 0, 0, 0);
      }
    }
  }
  int bnd1 = (m0 + 1) * KK, bnd2 = (m0 + 2) * KK;
#pragma unroll
  for (int mf = 0; mf < 4; ++mf) {
    float zp[4] = {0.f, 0.f, 0.f, 0.f};
#pragma unroll
    for (int nf = 0; nf < 4; ++nf) {
      int el = nf * 16 + c;
      float b1v = sb1v[el], w2v = sw2v[el];
#pragma unroll
      for (int r = 0; r < 4; ++r) {
        int rowg = r0 + w * 64 + mf * 16 + h * 4 + r;
        int sel = (rowg >= bnd1) + (rowg >= bnd2);
        float hh = acc[mf][nf][r] + smp[sel][el] + b1v;
        if (hh > 0.f) zp[r] += hh * w2v;
      }
    }
#pragma unroll
    for (int r = 0; r < 4; ++r) {
      float v = zp[r];
      v += __shfl_xor(v, 1, 64);
      v += __shfl_xor(v, 2, 64);
      v += __shfl_xor(v, 4, 64);
      v += __shfl_xor(v, 8, 64);
      if (c == 0)
        gpart[(size_t)(r0 + w * 64 + mf * 16 + h * 4 + r) * NET + et] = v;
    }
  }
}

// ------- Kernel E2: fused zred + mark (z = f64 sum of 12 partials + bs2; then sort, mark) -------
__global__ __launch_bounds__(256) void k_mark(
    const float* __restrict__ gpart, const float* __restrict__ bs2,
    double* __restrict__ z64, int* __restrict__ marks, int* __restrict__ mcnt) {
  int m = blockIdx.x;
  __shared__ double sk[256];
  __shared__ int sp[256];
  __shared__ int flag[256];
  int tid = threadIdx.x;
  flag[tid] = 0;
  if (tid < KK) {
    double s = 0.0;
#pragma unroll
    for (int i = 0; i < NET; ++i) s += (double)gpart[(size_t)(m * KK + tid) * NET + i];
    s += (double)bs2[0];
    z64[(size_t)m * KK + tid] = s;
    sk[tid] = s; sp[tid] = tid;
  } else { sk[tid] = -INFINITY; sp[tid] = 0x7fffffff; }
  __syncthreads();
  for (int k = 2; k <= 256; k <<= 1) {
    for (int j = k >> 1; j > 0; j >>= 1) {
      int i = tid, l = i ^ j;
      if (l > i) {
        double ka = sk[i], kb2 = sk[l];
        int ia = sp[i], ib = sp[l];
        bool lBefore = (kb2 > ka) || (kb2 == ka && ib < ia);
        bool iBefore = (ka > kb2) || (ka == kb2 && ia < ib);
        bool dir = ((i & k) == 0);
        bool sw = dir ? lBefore : iBefore;
        if (sw) { sk[i] = kb2; sk[l] = ka; sp[i] = ib; sp[l] = ia; }
      }
      __syncthreads();
    }
  }
  if (tid <= 120) {
    if (sk[tid] - sk[tid + 1] < DELTA) {
      flag[tid] = 1;
      atomicExch(&flag[tid + 1], 1);
    }
  }
  __syncthreads();
  if (tid <= 121 && flag[tid]) {
    int p = atomicAdd(mcnt, 1);
    if (p < MAXMARK) marks[p] = m * KK + sp[tid];
  }
}

// ------- Kernel E3: exact f64 rescore of marked candidates (in-place into z64) -------
__global__ __launch_bounds__(256) void k_rescore(
    const float* __restrict__ kb, const int* __restrict__ cidx,
    const double* __restrict__ mp64, const float* __restrict__ Ws1,
    const float* __restrict__ bs1, const float* __restrict__ Ws2,
    const float* __restrict__ bs2, const int* __restrict__ marks,
    const int* __restrict__ mcnt, double* __restrict__ z64) {
  int cnt = *mcnt; if (cnt > MAXMARK) cnt = MAXMARK;
  __shared__ float sc[DD];
  __shared__ double sred[256];
  int tid = threadIdx.x;
  for (int it = blockIdx.x; it < cnt; it += gridDim.x) {
    int r = marks[it];
    int m = r / KK;
    int row = cidx[r];
    for (int d = tid; d < DD; d += 256) sc[d] = kb[(size_t)row * DD + d];
    __syncthreads();
    double pz = 0.0;
    for (int e = tid; e < DD; e += 256) {
      double a = 0.0;
      for (int d = 0; d < DD; ++d) a += (double)sc[d] * (double)Ws1[(size_t)(DD + d) * DD + e];
      double hv = mp64[(size_t)m * DD + e] + a + (double)bs1[e];
      if (hv > 0) pz += hv * (double)Ws2[e];
    }
    sred[tid] = pz; __syncthreads();
    for (int s = 128; s > 0; s >>= 1) { if (tid < s) sred[tid] += sred[tid + s]; __syncthreads(); }
    if (tid == 0) z64[r] = sred[0] + (double)bs2[0];
    __syncthreads();
  }
}

// ---------------- Kernel F: per-mention top-100 of 200 (bitonic 256) ----------------
__global__ __launch_bounds__(256) void k_final(
    const double* __restrict__ z64, const int* __restrict__ cidx, float* __restrict__ out) {
  int m = blockIdx.x;
  __shared__ double sk[256];
  __shared__ int sp[256];
  int tid = threadIdx.x;
  if (tid < KK) { sk[tid] = z64[(size_t)m * KK + tid]; sp[tid] = tid; }
  else { sk[tid] = -INFINITY; sp[tid] = 0x7fffffff; }
  __syncthreads();
  for (int k = 2; k <= 256; k <<= 1) {
    for (int j = k >> 1; j > 0; j >>= 1) {
      int i = tid, l = i ^ j;
      if (l > i) {
        double ka = sk[i], kb2 = sk[l];
        int ia = sp[i], ib = sp[l];
        bool lBefore = (kb2 > ka) || (kb2 == ka && ib < ia);
        bool iBefore = (ka > kb2) || (ka == kb2 && ia < ib);
        bool dir = ((i & k) == 0);
        bool sw = dir ? lBefore : iBefore;
        if (sw) { sk[i] = kb2; sk[l] = ka; sp[i] = ib; sp[l] = ia; }
      }
      __syncthreads();
    }
  }
  if (tid < TOPK) {
    double z = sk[tid];
    out[(size_t)m * TOPK + tid] = (float)(1.0 / (1.0 + exp(-z)));
    out[(size_t)MM * TOPK + (size_t)m * TOPK + tid] = (float)cidx[(size_t)m * KK + sp[tid]];
  }
}

// ---------------- host ----------------
extern "C" void kernel_launch(void* const* d_in, const int* in_sizes, int n_in,
                              void* d_out, int out_size, void* d_ws, size_t ws_size,
                              hipStream_t stream) {
  const float* text  = (const float*)d_in[0];
  const float* kb    = (const float*)d_in[1];
  const float* Wret  = (const float*)d_in[2];
  const float* bret  = (const float*)d_in[3];
  const float* Ws1   = (const float*)d_in[4];
  const float* bs1   = (const float*)d_in[5];
  const float* Ws2   = (const float*)d_in[6];
  const float* bs2   = (const float*)d_in[7];
  const int* msent   = (const int*)d_in[8];
  const int* mstart  = (const int*)d_in[9];
  const int* mlen    = (const int*)d_in[10];
  float* out = (float*)d_out;

  char* ws = (char*)d_ws;
  size_t off = 0;
  auto alloc = [&](size_t bytes) -> void* {
    void* p = ws + off;
    off = (off + bytes + 255) & ~(size_t)255;
    return p;
  };
  double* q64  = (double*)alloc((size_t)MM * DD * 8);
  unsigned short* qb16 = (unsigned short*)alloc((size_t)MM * DD * 2);
  float*  tthr = (float*) alloc((size_t)MM * 4);
  double* mp64 = (double*)alloc((size_t)MM * DD * 8);
  float*  mp32 = (float*) alloc((size_t)MM * DD * 4);
  int*    cidx = (int*)   alloc((size_t)MM * KK * 4);
  double* z64  = (double*)alloc((size_t)MM * KK * 8);
  float*  gpart = (float*)alloc((size_t)MM * KK * NET * 4);
  int*    marks = (int*)  alloc((size_t)MAXMARK * 4);
  int*    mcnt  = (int*)  alloc(256);
  int*    gcnt  = (int*)  alloc((size_t)MM * 4);
  uint2*  gcand = (uint2*)alloc((size_t)MM * SURV_CAP * 8);
  unsigned short* Bth = (unsigned short*)alloc((size_t)DD * DD * 2);
  unsigned short* Btl = (unsigned short*)alloc((size_t)DD * DD * 2);
  float*  WretT = (float*)alloc((size_t)DD * DD * 4);
  (void)ws_size;

  dim3 gt(DD / 64, DD / 64);
  k_prepT<<<gt, 256, 0, stream>>>(Wret, WretT);
  k_prep<<<DD, 256, 0, stream>>>(Ws1, Bth, Btl);
  k_front<<<MM, 256, 0, stream>>>(text, msent, mstart, mlen, WretT, bret, Ws1,
                                  q64, qb16, tthr, mp64, mp32);

  hipMemsetAsync(gcnt, 0, (size_t)MM * 4, stream);
  k_sims_mfma<<<NKB / 64, 512, 0, stream>>>(qb16, kb, tthr, gcnt, gcand);
  k_select<<<MM, 256, 0, stream>>>(gcand, gcnt, kb, q64, cidx);

  k_score2<<<(MM * KK / 256) * NET, 256, 0, stream>>>(kb, cidx, mp32, Bth, Btl, bs1, Ws2, gpart);
  hipMemsetAsync(mcnt, 0, 4, stream);
  k_mark<<<MM, 256, 0, stream>>>(gpart, bs2, z64, marks, mcnt);
  k_rescore<<<2048, 256, 0, stream>>>(kb, cidx, mp64, Ws1, bs1, Ws2, bs2, marks, mcnt, z64);
  k_final<<<MM, 256, 0, stream>>>(z64, cidx, out);
}

// Round 18
// 1286.861 us; speedup vs baseline: 1.3682x; 1.0155x over previous
//
#include <hip/hip_runtime.h>
#include <cfloat>
#include <cmath>
#include <cstdint>

#define DD 768
#define MM 256
#define NKB 200000
#define SLEN 512
#define KK 200      // 2*top_k
#define TOPK 100
#define SURV_CAP 1024
#define RESC 232
#define THRC 2.70f
#define MAXMARK 32768
#define DELTA 4e-5
#define NET 12      // e-tiles of 64

typedef __attribute__((ext_vector_type(8))) short bf16x8;
typedef __attribute__((ext_vector_type(4))) float f32x4;

__device__ __forceinline__ unsigned short f2bf_rne(float x) {
  unsigned u = __float_as_uint(x);
  unsigned r = (u + 0x7FFFu + ((u >> 16) & 1u)) >> 16;
  return (unsigned short)r;
}
__device__ __forceinline__ float bf2f(unsigned short us) {
  return __uint_as_float(((unsigned)us) << 16);
}
__device__ __forceinline__ void splitbf(float x, unsigned short& hi, unsigned short& lo) {
  hi = f2bf_rne(x);
  lo = f2bf_rne(x - bf2f(hi));
}

// ---------------- Kernel PT: WretT[d][e] = Wret[e][d] (LDS-tiled, coalesced both sides) ----------------
__global__ __launch_bounds__(256) void k_prepT(
    const float* __restrict__ Wret, float* __restrict__ WretT) {
  __shared__ float tile[64][65];
  int e0 = blockIdx.x * 64, d0 = blockIdx.y * 64;
  int tid = threadIdx.x;
  int r = tid >> 6, cc = tid & 63;
  for (int i = 0; i < 64; i += 4)
    tile[r + i][cc] = Wret[(size_t)(e0 + r + i) * DD + d0 + cc];
  __syncthreads();
  for (int i = 0; i < 64; i += 4)
    WretT[(size_t)(d0 + r + i) * DD + e0 + cc] = tile[cc][r + i];
}

// ------- Kernel FRONT: fused mention-mean + query (via WretT, coalesced) + m_part -------
__global__ __launch_bounds__(256) void k_front(
    const float* __restrict__ text, const int* __restrict__ msent,
    const int* __restrict__ mstart, const int* __restrict__ mlen,
    const float* __restrict__ WretT, const float* __restrict__ bret,
    const float* __restrict__ Ws1,
    double* __restrict__ q64, unsigned short* __restrict__ qb16,
    float* __restrict__ tthr, double* __restrict__ mp64,
    float* __restrict__ mp32) {
  int m = blockIdx.x;
  __shared__ double sme[DD];
  __shared__ float snorm[256];
  int tid = threadIdx.x;
  {
    int sent = msent[m], st = mstart[m], ln = mlen[m];
    const float* base = text + (size_t)sent * SLEN * DD;
    for (int d = tid; d < DD; d += 256) {
      double acc = 0.0;
      for (int s = st; s <= st + ln; ++s) acc += (double)base[(size_t)s * DD + d];
      sme[d] = acc / (double)(ln + 1);
    }
  }
  __syncthreads();
  float nloc = 0.f;
  for (int e = tid; e < DD; e += 256) {
    double aq = (double)bret[e];
    double amp = 0.0;
    for (int d = 0; d < DD; ++d) {
      double md = sme[d];
      aq  += md * (double)WretT[(size_t)d * DD + e];
      amp += md * (double)Ws1[(size_t)d * DD + e];
    }
    q64[(size_t)m * DD + e] = aq;
    qb16[(size_t)m * DD + e] = f2bf_rne((float)aq);
    mp64[(size_t)m * DD + e] = amp;
    mp32[(size_t)m * DD + e] = (float)amp;
    nloc += (float)(aq * aq);
  }
  snorm[tid] = nloc; __syncthreads();
  for (int s = 128; s > 0; s >>= 1) {
    if (tid < s) snorm[tid] += snorm[tid + s];
    __syncthreads();
  }
  if (tid == 0) tthr[m] = THRC * sqrtf(snorm[0]);
}

// ---------------- Kernel P: split+transpose Ws1[D:] -> Bt_hi/Bt_lo [e][k] bf16 ----------------
__global__ __launch_bounds__(256) void k_prep(
    const float* __restrict__ Ws1, unsigned short* __restrict__ Bth,
    unsigned short* __restrict__ Btl) {
  int e = blockIdx.x;
  for (int k = threadIdx.x; k < DD; k += 256) {
    float x = Ws1[(size_t)(DD + k) * DD + e];
    unsigned short hi, lo;
    splitbf(x, hi, lo);
    Bth[(size_t)e * DD + k] = hi;
    Btl[(size_t)e * DD + k] = lo;
  }
}

// ------- Kernel C v5: sims = q @ kb^T via bf16 MFMA; 64-k steps, double-buffered B LDS,
// ONE barrier per 64-k step (12 total), 16 MFMAs/wave/barrier, 3-step-deep B prefetch.
// k-ascending MFMA order preserved (half0 then half1) -> bit-identical survivors.
__global__ __launch_bounds__(512) void k_sims_mfma(
    const unsigned short* __restrict__ qb, const float* __restrict__ kb,
    const float* __restrict__ tthr, int* __restrict__ gcnt,
    uint2* __restrict__ gcand) {
  __shared__ unsigned short Bs[2][64 * 64];   // 16 KB, swizzled, double-buffered
  __shared__ float sthr[256];
  int n0 = blockIdx.x * 64;
  int tid = threadIdx.x;
  int lane = tid & 63, w = tid >> 6;       // 8 waves
  int h = lane >> 4, c = lane & 15;
  if (tid < 256) sthr[tid] = tthr[tid];
  f32x4 acc[2][4] = {};
  const int brow = n0 + (tid >> 3);        // stage row (64 rows x 8 thr/row)
  const int bg   = tid & 7;                // 8 f32 group within 64-k
  const int bwoff = ((tid >> 3) * 128 + bg * 16) ^ (((tid >> 3) & 7) << 4);
  // load 8 f32 (two float4) for a 64-k step
  auto ldB = [&](int k0, float4 &d0, float4 &d1) {
    const float* s = kb + (size_t)brow * DD + k0 + bg * 8;
    d0 = *(const float4*)(s);
    d1 = *(const float4*)(s + 4);
  };
  auto stB = [&](int buf, const float4 &v0, const float4 &v1) {
    uint4 p;
    p.x = (unsigned)f2bf_rne(v0.x) | ((unsigned)f2bf_rne(v0.y) << 16);
    p.y = (unsigned)f2bf_rne(v0.z) | ((unsigned)f2bf_rne(v0.w) << 16);
    p.z = (unsigned)f2bf_rne(v1.x) | ((unsigned)f2bf_rne(v1.y) << 16);
    p.w = (unsigned)f2bf_rne(v1.z) | ((unsigned)f2bf_rne(v1.w) << 16);
    *(uint4*)((char*)Bs + buf * 8192 + bwoff) = p;
  };
  const unsigned short* qa0 = qb + (size_t)(w * 32 + c) * DD;
  const unsigned short* qa1 = qb + (size_t)(w * 32 + 16 + c) * DD;
  // prologue: buf0 = step0; pend1 = step1, pend2 = step2
  float4 c0, c1, p1a, p1b, p2a, p2b;
  ldB(0, c0, c1);
  stB(0, c0, c1);
  ldB(64, p1a, p1b);
  ldB(128, p2a, p2b);
  __syncthreads();
#pragma unroll
  for (int s = 0; s < 12; ++s) {
    int cur = s & 1;
    int k0 = s * 64;
    if (s + 1 < 12) stB(cur ^ 1, p1a, p1b);   // write NEXT buffer (readers done at prev barrier)
    p1a = p2a; p1b = p2b;
    if (s + 3 < 12) ldB((s + 3) * 64, p2a, p2b);
    // A-frags for this step (issue early; q is L2-hot)
    bf16x8 a00 = *(const bf16x8*)(qa0 + k0 + h * 8);
    bf16x8 a10 = *(const bf16x8*)(qa1 + k0 + h * 8);
    bf16x8 a01 = *(const bf16x8*)(qa0 + k0 + 32 + h * 8);
    bf16x8 a11 = *(const bf16x8*)(qa1 + k0 + 32 + h * 8);
    // half 0 (k0..k0+32)
#pragma unroll
    for (int nf = 0; nf < 4; ++nf) {
      int n = nf * 16 + c;
      int off = (n * 128 + h * 16) ^ ((n & 7) << 4);
      bf16x8 b = *(bf16x8*)((char*)Bs + cur * 8192 + off);
      acc[0][nf] = __builtin_amdgcn_mfma_f32_16x16x32_bf16(a00, b, acc[0][nf], 0, 0, 0);
      acc[1][nf] = __builtin_amdgcn_mfma_f32_16x16x32_bf16(a10, b, acc[1][nf], 0, 0, 0);
    }
    // half 1 (k0+32..k0+64)
#pragma unroll
    for (int nf = 0; nf < 4; ++nf) {
      int n = nf * 16 + c;
      int off = (n * 128 + 64 + h * 16) ^ ((n & 7) << 4);
      bf16x8 b = *(bf16x8*)((char*)Bs + cur * 8192 + off);
      acc[0][nf] = __builtin_amdgcn_mfma_f32_16x16x32_bf16(a01, b, acc[0][nf], 0, 0, 0);
      acc[1][nf] = __builtin_amdgcn_mfma_f32_16x16x32_bf16(a11, b, acc[1][nf], 0, 0, 0);
    }
    __syncthreads();   // next buffer written & visible; everyone done with Bs[cur]
  }
  // epilogue: C[row][col]: col = lane&15, row = (lane>>4)*4 + reg
#pragma unroll
  for (int mf = 0; mf < 2; ++mf)
#pragma unroll
    for (int nf = 0; nf < 4; ++nf)
#pragma unroll
      for (int r = 0; r < 4; ++r) {
        int row = w * 32 + mf * 16 + h * 4 + r;
        int col = n0 + nf * 16 + c;
        float v = acc[mf][nf][r];
        if (v > sthr[row]) {
          int p = atomicAdd(&gcnt[row], 1);
          if (p < SURV_CAP) gcand[(size_t)row * SURV_CAP + p] = make_uint2(__float_as_uint(v), (unsigned)col);
        }
      }
}

// ------- Kernel D: per-mention select top-200: sort survivors by f32 sims,
//         f64-rescore top RESC, exact sort, emit in sims-desc order -------
__global__ __launch_bounds__(256) void k_select(
    const uint2* __restrict__ gcand, const int* __restrict__ gcnt,
    const float* __restrict__ kb, const double* __restrict__ q64,
    int* __restrict__ cidx) {
  int m = blockIdx.x;
  __shared__ float skf[SURV_CAP];
  __shared__ int   sidx[SURV_CAP];
  __shared__ double sq[DD];
  __shared__ double skey[256];
  __shared__ int    skidx[256];
  int tid = threadIdx.x;
  int cnt = gcnt[m]; if (cnt > SURV_CAP) cnt = SURV_CAP;
  for (int d = tid; d < DD; d += 256) sq[d] = q64[(size_t)m * DD + d];
  for (int i = tid; i < SURV_CAP; i += 256) {
    if (i < cnt) {
      uint2 v = gcand[(size_t)m * SURV_CAP + i];
      skf[i] = __uint_as_float(v.x);
      sidx[i] = (int)v.y;
    } else { skf[i] = -FLT_MAX; sidx[i] = 0x7fffffff; }
  }
  __syncthreads();
  for (int k = 2; k <= SURV_CAP; k <<= 1) {
    for (int j = k >> 1; j > 0; j >>= 1) {
      for (int i = tid; i < SURV_CAP; i += 256) {
        int l = i ^ j;
        if (l > i) {
          float ka = skf[i], kb2 = skf[l];
          int ia = sidx[i], ib = sidx[l];
          bool lBefore = (kb2 > ka) || (kb2 == ka && ib < ia);
          bool iBefore = (ka > kb2) || (ka == kb2 && ia < ib);
          bool dir = ((i & k) == 0);
          bool sw = dir ? lBefore : iBefore;
          if (sw) { skf[i] = kb2; skf[l] = ka; sidx[i] = ib; sidx[l] = ia; }
        }
      }
      __syncthreads();
    }
  }
  int lane = tid & 63, wv = tid >> 6;
  for (int cpos = wv; cpos < RESC; cpos += 4) {
    int ci = sidx[cpos];
    double s;
    if (ci < NKB) {
      const float* krow = kb + (size_t)ci * DD;
      double acc = 0.0;
      for (int d = lane; d < DD; d += 64) acc += sq[d] * (double)krow[d];
      for (int off2 = 32; off2 > 0; off2 >>= 1) acc += __shfl_down(acc, off2, 64);
      s = acc;
    } else s = -INFINITY;
    if (lane == 0) { skey[cpos] = s; skidx[cpos] = ci; }
  }
  if (tid >= RESC && tid < 256) { skey[tid] = -INFINITY; skidx[tid] = 0x7fffffff; }
  __syncthreads();
  for (int k = 2; k <= 256; k <<= 1) {
    for (int j = k >> 1; j > 0; j >>= 1) {
      int i = tid, l = i ^ j;
      if (l > i) {
        double ka = skey[i], kb2 = skey[l];
        int ia = skidx[i], ib = skidx[l];
        bool lBefore = (kb2 > ka) || (kb2 == ka && ib < ia);
        bool iBefore = (ka > kb2) || (ka == kb2 && ia < ib);
        bool dir = ((i & k) == 0);
        bool sw = dir ? lBefore : iBefore;
        if (sw) { skey[i] = kb2; skey[l] = ka; skidx[i] = ib; skidx[l] = ia; }
      }
      __syncthreads();
    }
  }
  for (int cc = tid; cc < KK; cc += 256) {
    int v = skidx[cc];
    cidx[(size_t)m * KK + cc] = (v < NKB) ? v : 0;
  }
}

// ------- Kernel E v4: scorer GEMM partials — LDS-staged + T14 reg-prefetch -------
__global__ __launch_bounds__(256) void k_score2(
    const float* __restrict__ kb, const int* __restrict__ cidx,
    const float* __restrict__ mp32, const unsigned short* __restrict__ Bth,
    const unsigned short* __restrict__ Btl, const float* __restrict__ bs1,
    const float* __restrict__ Ws2, float* __restrict__ gpart) {
  __shared__ unsigned short Ah[256 * 32], Al[256 * 32];   // 16 KB each, swizzled
  __shared__ unsigned short Bh[64 * 32], Bl[64 * 32];     // 4 KB each, swizzled
  __shared__ float smp[3][64], sb1v[64], sw2v[64];
  __shared__ int srow[256];
  int p = blockIdx.x;
  int x = p & 7, j = p >> 3;
  int ct = x + 8 * (j / NET), et = j % NET;
  int r0 = ct * 256, e0 = et * 64;
  int tid = threadIdx.x, lane = tid & 63, w = tid >> 6;
  int h = lane >> 4, c = lane & 15;
  srow[tid] = cidx[r0 + tid];
  int m0 = r0 / KK;
  int mm1 = (m0 + 1 < MM) ? m0 + 1 : MM - 1;
  int mm2 = (m0 + 2 < MM) ? m0 + 2 : MM - 1;
  if (tid < 64) {
    smp[0][tid] = mp32[(size_t)m0 * DD + e0 + tid];
    smp[1][tid] = mp32[(size_t)mm1 * DD + e0 + tid];
    smp[2][tid] = mp32[(size_t)mm2 * DD + e0 + tid];
    sb1v[tid] = bs1[e0 + tid];
    sw2v[tid] = Ws2[e0 + tid];
  }
  __syncthreads();   // srow staged (needed for A addresses)
  const float* aaddr[8];
#pragma unroll
  for (int it = 0; it < 8; ++it) {
    int idx = tid + it * 256;
    int rr = idx >> 3, f4 = idx & 7;
    aaddr[it] = kb + (size_t)srow[rr] * DD + f4 * 4;
  }
  const int be = tid >> 2, bk8 = tid & 3;
  const unsigned short* bhaddr = Bth + (size_t)(e0 + be) * DD + bk8 * 8;
  const unsigned short* bladdr = Btl + (size_t)(e0 + be) * DD + bk8 * 8;
  float4 pa[8];
  uint4 pbh, pbl;
#pragma unroll
  for (int it = 0; it < 8; ++it) pa[it] = *(const float4*)(aaddr[it]);
  pbh = *(const uint4*)(bhaddr);
  pbl = *(const uint4*)(bladdr);
  f32x4 acc[4][4] = {};
  for (int k0 = 0; k0 < DD; k0 += 32) {
    __syncthreads();   // prev MFMA done reading LDS
#pragma unroll
    for (int it = 0; it < 8; ++it) {
      int idx = tid + it * 256;
      int rr = idx >> 3, f4 = idx & 7;
      float4 v = pa[it];
      unsigned short h0, h1, h2, h3, l0, l1, l2, l3;
      splitbf(v.x, h0, l0); splitbf(v.y, h1, l1);
      splitbf(v.z, h2, l2); splitbf(v.w, h3, l3);
      uint2 ph, pl;
      ph.x = (unsigned)h0 | ((unsigned)h1 << 16); ph.y = (unsigned)h2 | ((unsigned)h3 << 16);
      pl.x = (unsigned)l0 | ((unsigned)l1 << 16); pl.y = (unsigned)l2 | ((unsigned)l3 << 16);
      int off = (rr * 64 + f4 * 8) ^ ((rr & 7) << 4);
      *(uint2*)((char*)Ah + off) = ph;
      *(uint2*)((char*)Al + off) = pl;
    }
    {
      int off = (be * 64 + bk8 * 16) ^ ((be & 7) << 4);
      *(uint4*)((char*)Bh + off) = pbh;
      *(uint4*)((char*)Bl + off) = pbl;
    }
    if (k0 + 32 < DD) {
#pragma unroll
      for (int it = 0; it < 8; ++it) pa[it] = *(const float4*)(aaddr[it] + k0 + 32);
      pbh = *(const uint4*)(bhaddr + k0 + 32);
      pbl = *(const uint4*)(bladdr + k0 + 32);
    }
    __syncthreads();   // LDS ready
    bf16x8 ah[4], al[4];
#pragma unroll
    for (int mf = 0; mf < 4; ++mf) {
      int rr = w * 64 + mf * 16 + c;
      int off = (rr * 64 + h * 16) ^ ((rr & 7) << 4);
      ah[mf] = *(bf16x8*)((char*)Ah + off);
      al[mf] = *(bf16x8*)((char*)Al + off);
    }
#pragma unroll
    for (int nf = 0; nf < 4; ++nf) {
      int e = nf * 16 + c;
      int off = (e * 64 + h * 16) ^ ((e & 7) << 4);
      bf16x8 bh = *(bf16x8*)((char*)Bh + off);
      bf16x8 bl = *(bf16x8*)((char*)Bl + off);
#pragma unroll
      for (int mf = 0; mf < 4; ++mf) {
        acc[mf][nf] = __builtin_amdgcn_mfma_f32_16x16x32_bf16(ah[mf], bh, acc[mf][nf], 0, 0, 0);
        acc[mf][nf] = __builtin_amdgcn_mfma_f32_16x16x32_bf16(ah[mf], bl, acc[mf][nf], 0, 0, 0);
        acc[mf][nf] = __builtin_amdgcn_mfma_f32_16x16x32_bf16(al[mf], bh, acc[mf][nf], 0, 0, 0);
      }
    }
  }
  int bnd1 = (m0 + 1) * KK, bnd2 = (m0 + 2) * KK;
#pragma unroll
  for (int mf = 0; mf < 4; ++mf) {
    float zp[4] = {0.f, 0.f, 0.f, 0.f};
#pragma unroll
    for (int nf = 0; nf < 4; ++nf) {
      int el = nf * 16 + c;
      float b1v = sb1v[el], w2v = sw2v[el];
#pragma unroll
      for (int r = 0; r < 4; ++r) {
        int rowg = r0 + w * 64 + mf * 16 + h * 4 + r;
        int sel = (rowg >= bnd1) + (rowg >= bnd2);
        float hh = acc[mf][nf][r] + smp[sel][el] + b1v;
        if (hh > 0.f) zp[r] += hh * w2v;
      }
    }
#pragma unroll
    for (int r = 0; r < 4; ++r) {
      float v = zp[r];
      v += __shfl_xor(v, 1, 64);
      v += __shfl_xor(v, 2, 64);
      v += __shfl_xor(v, 4, 64);
      v += __shfl_xor(v, 8, 64);
      if (c == 0)
        gpart[(size_t)(r0 + w * 64 + mf * 16 + h * 4 + r) * NET + et] = v;
    }
  }
}

// ------- Kernel E2: fused zred + mark (z = f64 sum of 12 partials + bs2; then sort, mark) -------
__global__ __launch_bounds__(256) void k_mark(
    const float* __restrict__ gpart, const float* __restrict__ bs2,
    double* __restrict__ z64, int* __restrict__ marks, int* __restrict__ mcnt) {
  int m = blockIdx.x;
  __shared__ double sk[256];
  __shared__ int sp[256];
  __shared__ int flag[256];
  int tid = threadIdx.x;
  flag[tid] = 0;
  if (tid < KK) {
    double s = 0.0;
#pragma unroll
    for (int i = 0; i < NET; ++i) s += (double)gpart[(size_t)(m * KK + tid) * NET + i];
    s += (double)bs2[0];
    z64[(size_t)m * KK + tid] = s;
    sk[tid] = s; sp[tid] = tid;
  } else { sk[tid] = -INFINITY; sp[tid] = 0x7fffffff; }
  __syncthreads();
  for (int k = 2; k <= 256; k <<= 1) {
    for (int j = k >> 1; j > 0; j >>= 1) {
      int i = tid, l = i ^ j;
      if (l > i) {
        double ka = sk[i], kb2 = sk[l];
        int ia = sp[i], ib = sp[l];
        bool lBefore = (kb2 > ka) || (kb2 == ka && ib < ia);
        bool iBefore = (ka > kb2) || (ka == kb2 && ia < ib);
        bool dir = ((i & k) == 0);
        bool sw = dir ? lBefore : iBefore;
        if (sw) { sk[i] = kb2; sk[l] = ka; sp[i] = ib; sp[l] = ia; }
      }
      __syncthreads();
    }
  }
  if (tid <= 120) {
    if (sk[tid] - sk[tid + 1] < DELTA) {
      flag[tid] = 1;
      atomicExch(&flag[tid + 1], 1);
    }
  }
  __syncthreads();
  if (tid <= 121 && flag[tid]) {
    int p = atomicAdd(mcnt, 1);
    if (p < MAXMARK) marks[p] = m * KK + sp[tid];
  }
}

// ------- Kernel E3: exact f64 rescore of marked candidates (in-place into z64) -------
__global__ __launch_bounds__(256) void k_rescore(
    const float* __restrict__ kb, const int* __restrict__ cidx,
    const double* __restrict__ mp64, const float* __restrict__ Ws1,
    const float* __restrict__ bs1, const float* __restrict__ Ws2,
    const float* __restrict__ bs2, const int* __restrict__ marks,
    const int* __restrict__ mcnt, double* __restrict__ z64) {
  int cnt = *mcnt; if (cnt > MAXMARK) cnt = MAXMARK;
  __shared__ float sc[DD];
  __shared__ double sred[256];
  int tid = threadIdx.x;
  for (int it = blockIdx.x; it < cnt; it += gridDim.x) {
    int r = marks[it];
    int m = r / KK;
    int row = cidx[r];
    for (int d = tid; d < DD; d += 256) sc[d] = kb[(size_t)row * DD + d];
    __syncthreads();
    double pz = 0.0;
    for (int e = tid; e < DD; e += 256) {
      double a = 0.0;
      for (int d = 0; d < DD; ++d) a += (double)sc[d] * (double)Ws1[(size_t)(DD + d) * DD + e];
      double hv = mp64[(size_t)m * DD + e] + a + (double)bs1[e];
      if (hv > 0) pz += hv * (double)Ws2[e];
    }
    sred[tid] = pz; __syncthreads();
    for (int s = 128; s > 0; s >>= 1) { if (tid < s) sred[tid] += sred[tid + s]; __syncthreads(); }
    if (tid == 0) z64[r] = sred[0] + (double)bs2[0];
    __syncthreads();
  }
}

// ---------------- Kernel F: per-mention top-100 of 200 (bitonic 256) ----------------
__global__ __launch_bounds__(256) void k_final(
    const double* __restrict__ z64, const int* __restrict__ cidx, float* __restrict__ out) {
  int m = blockIdx.x;
  __shared__ double sk[256];
  __shared__ int sp[256];
  int tid = threadIdx.x;
  if (tid < KK) { sk[tid] = z64[(size_t)m * KK + tid]; sp[tid] = tid; }
  else { sk[tid] = -INFINITY; sp[tid] = 0x7fffffff; }
  __syncthreads();
  for (int k = 2; k <= 256; k <<= 1) {
    for (int j = k >> 1; j > 0; j >>= 1) {
      int i = tid, l = i ^ j;
      if (l > i) {
        double ka = sk[i], kb2 = sk[l];
        int ia = sp[i], ib = sp[l];
        bool lBefore = (kb2 > ka) || (kb2 == ka && ib < ia);
        bool iBefore = (ka > kb2) || (ka == kb2 && ia < ib);
        bool dir = ((i & k) == 0);
        bool sw = dir ? lBefore : iBefore;
        if (sw) { sk[i] = kb2; sk[l] = ka; sp[i] = ib; sp[l] = ia; }
      }
      __syncthreads();
    }
  }
  if (tid < TOPK) {
    double z = sk[tid];
    out[(size_t)m * TOPK + tid] = (float)(1.0 / (1.0 + exp(-z)));
    out[(size_t)MM * TOPK + (size_t)m * TOPK + tid] = (float)cidx[(size_t)m * KK + sp[tid]];
  }
}

// ---------------- host ----------------
extern "C" void kernel_launch(void* const* d_in, const int* in_sizes, int n_in,
                              void* d_out, int out_size, void* d_ws, size_t ws_size,
                              hipStream_t stream) {
  const float* text  = (const float*)d_in[0];
  const float* kb    = (const float*)d_in[1];
  const float* Wret  = (const float*)d_in[2];
  const float* bret  = (const float*)d_in[3];
  const float* Ws1   = (const float*)d_in[4];
  const float* bs1   = (const float*)d_in[5];
  const float* Ws2   = (const float*)d_in[6];
  const float* bs2   = (const float*)d_in[7];
  const int* msent   = (const int*)d_in[8];
  const int* mstart  = (const int*)d_in[9];
  const int* mlen    = (const int*)d_in[10];
  float* out = (float*)d_out;

  char* ws = (char*)d_ws;
  size_t off = 0;
  auto alloc = [&](size_t bytes) -> void* {
    void* p = ws + off;
    off = (off + bytes + 255) & ~(size_t)255;
    return p;
  };
  double* q64  = (double*)alloc((size_t)MM * DD * 8);
  unsigned short* qb16 = (unsigned short*)alloc((size_t)MM * DD * 2);
  float*  tthr = (float*) alloc((size_t)MM * 4);
  double* mp64 = (double*)alloc((size_t)MM * DD * 8);
  float*  mp32 = (float*) alloc((size_t)MM * DD * 4);
  int*    cidx = (int*)   alloc((size_t)MM * KK * 4);
  double* z64  = (double*)alloc((size_t)MM * KK * 8);
  float*  gpart = (float*)alloc((size_t)MM * KK * NET * 4);
  int*    marks = (int*)  alloc((size_t)MAXMARK * 4);
  int*    mcnt  = (int*)  alloc(256);
  int*    gcnt  = (int*)  alloc((size_t)MM * 4);
  uint2*  gcand = (uint2*)alloc((size_t)MM * SURV_CAP * 8);
  unsigned short* Bth = (unsigned short*)alloc((size_t)DD * DD * 2);
  unsigned short* Btl = (unsigned short*)alloc((size_t)DD * DD * 2);
  float*  WretT = (float*)alloc((size_t)DD * DD * 4);
  (void)ws_size;

  dim3 gt(DD / 64, DD / 64);
  k_prepT<<<gt, 256, 0, stream>>>(Wret, WretT);
  k_prep<<<DD, 256, 0, stream>>>(Ws1, Bth, Btl);
  k_front<<<MM, 256, 0, stream>>>(text, msent, mstart, mlen, WretT, bret, Ws1,
                                  q64, qb16, tthr, mp64, mp32);

  hipMemsetAsync(gcnt, 0, (size_t)MM * 4, stream);
  k_sims_mfma<<<NKB / 64, 512, 0, stream>>>(qb16, kb, tthr, gcnt, gcand);
  k_select<<<MM, 256, 0, stream>>>(gcand, gcnt, kb, q64, cidx);

  k_score2<<<(MM * KK / 256) * NET, 256, 0, stream>>>(kb, cidx, mp32, Bth, Btl, bs1, Ws2, gpart);
  hipMemsetAsync(mcnt, 0, 4, stream);
  k_mark<<<MM, 256, 0, stream>>>(gpart, bs2, z64, marks, mcnt);
  k_rescore<<<2048, 256, 0, stream>>>(kb, cidx, mp64, Ws1, bs1, Ws2, bs2, marks, mcnt, z64);
  k_final<<<MM, 256, 0, stream>>>(z64, cidx, out);
}